// Round 7
// baseline (140.176 us; speedup 1.0000x reference)
//
#include <hip/hip_runtime.h>

// ---------------------------------------------------------------------------
// DeltaModel: B=256, L=2048, H=V=64.
//  (1) hs/k/v/q depend only on token id (V=64) -> 64-entry tables.
//  (2) r = M_N q -> backward scan with y_a = k_a . u for all 64 keys:
//        s = y[b_t];  y -= s * G[.][b_t];  r += s * v[b_t]
//      G[a][b] = k_a.k_b. Chain = readlane -> fma.
//  R5 post-mortem: dummy token 64 reached v_readlane's lane select (UB,
//  persistent-garbage symptom: right first launch, consistently wrong after).
//  R6: dummy step = zero bufA[0] IN REGISTERS at prime; every readlane select
//  is a real seq token (<64). Keeps 5 VALU + 1 ds_read_b64 per step (tokens
//  extracted once to SGPRs, carried as next chunk's consume selects).
// ---------------------------------------------------------------------------

#define DPP_ADD_F32(x, ctrl, rm, bm, bc)                                      \
  (x) = (x) + __int_as_float(__builtin_amdgcn_update_dpp(                     \
            0, __float_as_int(x), (ctrl), (rm), (bm), (bc)))

__device__ __forceinline__ float wave_sum64(float x) {
  DPP_ADD_F32(x, 0x111, 0xf, 0xf, true);   // row_shr:1
  DPP_ADD_F32(x, 0x112, 0xf, 0xf, true);   // row_shr:2
  DPP_ADD_F32(x, 0x114, 0xf, 0xf, true);   // row_shr:4
  DPP_ADD_F32(x, 0x118, 0xf, 0xf, true);   // row_shr:8
  DPP_ADD_F32(x, 0x142, 0xa, 0xf, false);  // row_bcast:15
  DPP_ADD_F32(x, 0x143, 0xc, 0xf, false);  // row_bcast:31 -> lane 63 total
  return __int_as_float(__builtin_amdgcn_readlane(__float_as_int(x), 63));
}

__device__ __forceinline__ float readlane_f(float x, int lane) {
  return __int_as_float(__builtin_amdgcn_readlane(__float_as_int(x), lane));
}

// ---------------------------------------------------------------------------
// Kernel A: per-token tables k_n, v, q (weights staged in padded LDS).
// ---------------------------------------------------------------------------
__global__ __launch_bounds__(64) void build_tables(
    const float* __restrict__ embed, const float* __restrict__ W1,
    const float* __restrict__ b1, const float* __restrict__ W2,
    const float* __restrict__ b2, const float* __restrict__ gamma,
    const float* __restrict__ beta, const float* __restrict__ Wk,
    const float* __restrict__ Wv, const float* __restrict__ Wq,
    float* __restrict__ k_tab, float* __restrict__ v_tab,
    float* __restrict__ q_tab) {
  __shared__ float Wbuf[8448];
  __shared__ float e_s[64];
  __shared__ float f1_s[128];
  __shared__ float hs_s[64];
  const int tok = blockIdx.x;
  const int l = threadIdx.x;

  const float e = embed[tok * 64 + l];
  e_s[l] = e;
#pragma unroll 8
  for (int i = 0; i < 128; ++i) Wbuf[i * 65 + l] = W1[i * 64 + l];
  __syncthreads();

  float a0 = b1[l], a1 = b1[l + 64];
#pragma unroll
  for (int h = 0; h < 64; ++h) {
    a0 = fmaf(e_s[h], Wbuf[l * 65 + h], a0);
    a1 = fmaf(e_s[h], Wbuf[(l + 64) * 65 + h], a1);
  }
  f1_s[l] = fmaxf(a0, 0.f);
  f1_s[l + 64] = fmaxf(a1, 0.f);
  __syncthreads();

#pragma unroll 8
  for (int i = 0; i < 128; ++i)
    Wbuf[(i >> 1) * 131 + (i & 1) * 64 + l] = W2[i * 64 + l];
  __syncthreads();

  float acc = b2[l];
#pragma unroll
  for (int j = 0; j < 128; ++j) acc = fmaf(f1_s[j], Wbuf[l * 131 + j], acc);
  const float hval = e + acc;

  const float mu = wave_sum64(hval) * (1.f / 64.f);
  const float d = hval - mu;
  const float var = wave_sum64(d * d) * (1.f / 64.f);
  const float hs = d * (1.f / sqrtf(var + 1e-5f)) * gamma[l] + beta[l];
  hs_s[l] = hs;
  __syncthreads();

#pragma unroll 8
  for (int i = 0; i < 64; ++i) {
    Wbuf[i * 65 + l] = Wk[i * 64 + l];
    Wbuf[4224 + i * 65 + l] = Wv[i * 64 + l];
  }
  __syncthreads();
  float kk = 0.f, vv = 0.f;
#pragma unroll
  for (int h = 0; h < 64; ++h) {
    kk = fmaf(hs_s[h], Wbuf[l * 65 + h], kk);
    vv = fmaf(hs_s[h], Wbuf[4224 + l * 65 + h], vv);
  }
  __syncthreads();
#pragma unroll 8
  for (int i = 0; i < 64; ++i) Wbuf[i * 65 + l] = Wq[i * 64 + l];
  __syncthreads();
  float qq = 0.f;
#pragma unroll
  for (int h = 0; h < 64; ++h) qq = fmaf(hs_s[h], Wbuf[l * 65 + h], qq);

  float nrm = fmaxf(sqrtf(wave_sum64(kk * kk)), 1e-12f);
  k_tab[tok * 64 + l] = kk / nrm;
  v_tab[tok * 64 + l] = vv;
  q_tab[tok * 64 + l] = qq;
}

// ---------------------------------------------------------------------------
// Kernel B: GV[a][l] = {G[a][l], v[a][l]} packed float2; KQ[a][l] = q_a.k_l.
// ---------------------------------------------------------------------------
__global__ __launch_bounds__(64) void build_gram(
    const float* __restrict__ k_tab, const float* __restrict__ q_tab,
    const float* __restrict__ v_tab, float2* __restrict__ GV,
    float* __restrict__ KQ) {
  __shared__ float k_s[4160];
  __shared__ float q_s[64];
  const int a = blockIdx.x;
  const int l = threadIdx.x;
#pragma unroll 8
  for (int i = 0; i < 64; ++i) k_s[i * 65 + l] = k_tab[i * 64 + l];
  q_s[l] = q_tab[a * 64 + l];
  __syncthreads();
  float g = 0.f, kq = 0.f;
#pragma unroll
  for (int h = 0; h < 64; ++h) {
    g = fmaf(k_s[a * 65 + h], k_s[l * 65 + h], g);
    kq = fmaf(q_s[h], k_s[l * 65 + h], kq);
  }
  GV[a * 64 + l] = make_float2(g, v_tab[a * 64 + l]);
  KQ[a * 64 + l] = kq;
}

// ---------------------------------------------------------------------------
// Kernel C: per-batch scan + head. One wave per batch; lane a owns y_a.
// 16-step chunks: extract next chunk's 16 tokens to SGPRs (snxt), prefetch
// their GV columns into the spare buffer, consume this chunk with carried
// SGPR selects (ssel, always real tokens < 64), then ssel <- snxt.
// ---------------------------------------------------------------------------

#define CHUNK(CONS, PREF, TV, PB)                                             \
  {                                                                           \
    int snxt[16];                                                             \
    _Pragma("unroll") for (int j = 0; j < 16; ++j) snxt[j] =                  \
        __builtin_amdgcn_readlane((TV), (PB) + j);                            \
    _Pragma("unroll") for (int j = 0; j < 16; ++j) PREF[j] =                  \
        GV_s[snxt[j] * 64 + l];                                               \
    _Pragma("unroll") for (int j = 0; j < 16; ++j) {                          \
      const float s = readlane_f(y, ssel[j]);                                 \
      y = fmaf(-s, CONS[j].x, y);                                             \
      r = fmaf(s, CONS[j].y, r);                                              \
    }                                                                         \
    _Pragma("unroll") for (int j = 0; j < 16; ++j) ssel[j] = snxt[j];         \
  }

__global__ __launch_bounds__(64, 1) void scan_head(
    const int* __restrict__ seq, const float2* __restrict__ GVg,
    const float* __restrict__ KQ, const float* __restrict__ Wrp,
    const float* __restrict__ brp, const float* __restrict__ Wout,
    const float* __restrict__ bout, float* __restrict__ out) {
  __shared__ float2 GV_s[4160];  // 64 token rows + spare row (staged zeros)
  __shared__ float tmp[64];
  const int b = blockIdx.x;
  const int l = threadIdx.x;

#pragma unroll
  for (int i = 0; i < 32; ++i)
    ((float4*)GV_s)[l + 64 * i] = ((const float4*)GVg)[l + 64 * i];
  GV_s[4096 + l] = make_float2(0.f, 0.f);

  const int* tokp = seq + b * 2048;
  int tok_cur = tokp[2047 - l];       // body 0: lane m <-> step m, t = 2047-m
  int tok_nxt = tokp[2047 - 64 - l];  // body 1
  __syncthreads();

  const int qt = __builtin_amdgcn_readlane(tok_cur, 0);  // t=2047 token -> q
  float y = KQ[qt * 64 + l];                             // y_a = k_a . q
  float r = 0.f;

  float2 bufA[16], bufB[16];
  int ssel[16];
  {  // prime: tokens + columns for steps 0..15
#pragma unroll
    for (int j = 0; j < 16; ++j)
      ssel[j] = __builtin_amdgcn_readlane(tok_cur, j);
#pragma unroll
    for (int j = 0; j < 16; ++j) bufA[j] = GV_s[ssel[j] * 64 + l];
  }
  // Step 0 is the dummy (t=2047 is the query position, not applied): zero its
  // column IN REGISTERS -> y,r unchanged; ssel[0] stays a real token (<64),
  // so every v_readlane lane-select is in range (no UB).
  bufA[0] = make_float2(0.f, 0.f);

  for (int n = 0; n < 32; ++n) {
    const int tok_fut = (n + 2 <= 31) ? tokp[2047 - 64 * (n + 2) - l] : 0;
    CHUNK(bufA, bufB, tok_cur, 16);  // consume steps 0-15, pref 16-31
    CHUNK(bufB, bufA, tok_cur, 32);
    CHUNK(bufA, bufB, tok_cur, 48);
    CHUNK(bufB, bufA, tok_nxt, 0);   // pref next body's first chunk
    tok_cur = tok_nxt;
    tok_nxt = tok_fut;
  }

  // Head: r -> Wrp -> Wout (weights staged padded into GV_s memory)
  float* Wb = (float*)GV_s;
  tmp[l] = r;
#pragma unroll 8
  for (int i = 0; i < 64; ++i) {
    Wb[i * 65 + l] = Wrp[i * 64 + l];
    Wb[4160 + i * 65 + l] = Wout[i * 64 + l];
  }
  __syncthreads();
  float acc = brp[l];
#pragma unroll
  for (int j = 0; j < 64; ++j) acc = fmaf(tmp[j], Wb[l * 65 + j], acc);
  __syncthreads();
  tmp[l] = acc;
  __syncthreads();
  float o = bout[l];
#pragma unroll
  for (int i = 0; i < 64; ++i) o = fmaf(tmp[i], Wb[4160 + l * 65 + i], o);
  out[b * 64 + l] = o;
}

extern "C" void kernel_launch(void* const* d_in, const int* in_sizes, int n_in,
                              void* d_out, int out_size, void* d_ws,
                              size_t ws_size, hipStream_t stream) {
  const int* seq = (const int*)d_in[0];
  const float* embed = (const float*)d_in[1];
  const float* W1 = (const float*)d_in[2];
  const float* b1 = (const float*)d_in[3];
  const float* W2 = (const float*)d_in[4];
  const float* b2 = (const float*)d_in[5];
  const float* gamma = (const float*)d_in[6];
  const float* beta = (const float*)d_in[7];
  const float* Wk = (const float*)d_in[8];
  const float* Wv = (const float*)d_in[9];
  const float* Wq = (const float*)d_in[10];
  const float* Wrp = (const float*)d_in[11];
  const float* brp = (const float*)d_in[12];
  const float* Wout = (const float*)d_in[13];
  const float* bout = (const float*)d_in[14];

  float* wsf = (float*)d_ws;
  float* k_tab = wsf;                   // 4096
  float* v_tab = wsf + 4096;            // 4096
  float* q_tab = wsf + 8192;            // 4096
  float2* GV = (float2*)(wsf + 12288);  // 4096 float2
  float* KQ = wsf + 20480;              // 4096

  build_tables<<<64, 64, 0, stream>>>(embed, W1, b1, W2, b2, gamma, beta, Wk,
                                      Wv, Wq, k_tab, v_tab, q_tab);
  build_gram<<<64, 64, 0, stream>>>(k_tab, q_tab, v_tab, GV, KQ);
  scan_head<<<256, 64, 0, stream>>>(seq, GV, KQ, Wrp, brp, Wout, bout,
                                    (float*)d_out);
}